// Round 16
// baseline (107.039 us; speedup 1.0000x reference)
//
#include <hip/hip_runtime.h>
#include <hip/hip_bf16.h>

// Model dims (fixed by the reference)
#define R_ 64
#define S_ 32
#define T_ 50
#define E_ 512
#define U_ 20
#define D_ 532   // E + U
#define L_ 9
#define NSENT (R_ * S_)   // 2048

#define PCHUNK 128
#define NCG 5
#define NKG 5

// flag slots (64B-padded) in ws, zeroed by kernel A block 0
#define FG1 0
#define FG2 16
#define FD  32

typedef __attribute__((ext_vector_type(8))) short bf16x8;
typedef __attribute__((ext_vector_type(4))) float f32x4;

__device__ __forceinline__ float selu_f(float x) {
    const float scale = 1.0507009873554805f;
    const float alpha = 1.6732632423543772f;
    return x > 0.0f ? scale * x : scale * alpha * expm1f(x);
}

__device__ __forceinline__ void spin_until(const int* f, int target) {
    while (__hip_atomic_load(f, __ATOMIC_RELAXED, __HIP_MEMORY_SCOPE_AGENT) < target)
        __builtin_amdgcn_s_sleep(2);
}

// Kernel A: blocks [0,2048) per-sentence masked token-mean -> bf16 (measured ~29.5us,
// random-gather service bound). blocks [2048,2560): w transpose-convert -> bf16 wT.
__global__ __launch_bounds__(256) void k_fused_A(
        const int* __restrict__ inputs,
        const float* __restrict__ emb,
        const float* __restrict__ w_sent,
        const float* __restrict__ w_rev,
        __hip_bfloat16* __restrict__ sent_bf,
        __hip_bfloat16* __restrict__ wT,
        float* __restrict__ smask,
        int* __restrict__ fl)
{
    const int tid = threadIdx.x;

    if (blockIdx.x >= NSENT) {
        __shared__ float tile[32][33];
        const int b = blockIdx.x - NSENT;
        const int z = b >> 8;
        const float* w = z ? w_rev : w_sent;
        __hip_bfloat16* o = wT + (size_t)z * E_ * E_;
        const int bb = b & 255;
        const int tx = tid & 31, ty = tid >> 5;
        const int k0 = (bb >> 4) * 32, n0 = (bb & 15) * 32;
        #pragma unroll
        for (int i = 0; i < 4; ++i)
            tile[ty + 8 * i][tx] = w[(size_t)(k0 + ty + 8 * i) * E_ + n0 + tx];
        __syncthreads();
        #pragma unroll
        for (int i = 0; i < 4; ++i)
            o[(size_t)(n0 + ty + 8 * i) * E_ + k0 + tx] = __float2bfloat16(tile[tx][ty + 8 * i]);
        return;
    }

    if (blockIdx.x == 0 && tid < 48) fl[tid] = 0;

    const int sid = blockIdx.x;
    const int base = sid * T_;
    float2 acc = {0.f, 0.f};
    int cnt = 0;
    for (int t = 0; t < T_; ++t) {
        const int tok = inputs[base + t];
        const float m = (tok != 0) ? 1.0f : 0.0f;
        cnt += (tok != 0);
        const float2 v = ((const float2*)(emb + (size_t)tok * E_))[tid];
        acc.x = fmaf(v.x, m, acc.x);
        acc.y = fmaf(v.y, m, acc.y);
    }
    const float inv = 1.0f / fmaxf((float)cnt, 1.0f);
    __hip_bfloat162 h2;
    h2.x = __float2bfloat16(acc.x * inv);
    h2.y = __float2bfloat16(acc.y * inv);
    ((__hip_bfloat162*)(sent_bf + (size_t)sid * E_))[tid] = h2;
    if (tid == 0) smask[sid] = (cnt > 0) ? 1.0f : 0.0f;
}

// Kernel T (tail): 256 blocks, 1 block/CU, all co-resident -> safe flag chaining.
// Phase G1 (all 256): sent GEMM + masked-mean -> mrev.   signal FG1
// Phase G2 (blocks 0..7): rev GEMM -> p_batch + pbar.    wait FG1==256, signal FG2
// Phase D  (blocks 0..24): product head partials + last-block finalize (FD).
__global__ __launch_bounds__(256) void k_tail(
        const __hip_bfloat16* __restrict__ sent_bf, // [2048,512]
        const __hip_bfloat16* __restrict__ wT,      // [2][512][512]
        const float* __restrict__ b_sent,
        const float* __restrict__ smask,
        const float* __restrict__ b_rev,
        const float* __restrict__ user_feats,
        const float* __restrict__ user_w,
        const float* __restrict__ w_prod,
        const float* __restrict__ b_prod,
        const float* __restrict__ w_pff,
        const float* __restrict__ b_pff,
        const float* __restrict__ w_rff,
        const float* __restrict__ b_rff,
        __hip_bfloat16* __restrict__ mrev,          // ws [64,512]
        float* __restrict__ p_batch,                // ws [64,532]
        float* __restrict__ pbar,                   // ws [532]
        float* __restrict__ part,                   // ws [NKG][532]
        int* __restrict__ fl,                       // ws flags
        float* __restrict__ out_p,                  // [9]
        float* __restrict__ out_r)                  // [64]
{
    __shared__ __align__(16) char smem[24576];
    const int tid = threadIdx.x;
    const int b   = blockIdx.x;
    const int wid  = tid >> 6;
    const int lane = tid & 63;
    const int wm = wid >> 1, wn = wid & 1;
    const int fr = lane & 15;
    const int kg = (lane >> 4) * 8;
    const int rq = (lane >> 4) * 4;
    const int srow = tid >> 2;
    const int soff = (tid & 3) * 8;

    // ================= Phase G1: all 256 blocks =================
    {
        short (*As)[40] = (short(*)[40])smem;
        short (*Bs)[40] = (short(*)[40])(smem + 5120);
        const int bm = (b >> 3) * 64, bn = (b & 7) * 64;
        const short* Ag  = (const short*)sent_bf;
        const short* Btg = (const short*)wT;

        f32x4 acc[2][2];
        #pragma unroll
        for (int i = 0; i < 2; ++i)
            #pragma unroll
            for (int j = 0; j < 2; ++j) acc[i][j] = (f32x4){0.f, 0.f, 0.f, 0.f};

        for (int k0 = 0; k0 < E_; k0 += 32) {
            __syncthreads();
            *(bf16x8*)&As[srow][soff] = *(const bf16x8*)&Ag[(size_t)(bm + srow) * E_ + k0 + soff];
            *(bf16x8*)&Bs[srow][soff] = *(const bf16x8*)&Btg[(size_t)(bn + srow) * E_ + k0 + soff];
            __syncthreads();
            bf16x8 af0 = *(const bf16x8*)&As[wm * 32 + fr][kg];
            bf16x8 af1 = *(const bf16x8*)&As[wm * 32 + 16 + fr][kg];
            bf16x8 bf0 = *(const bf16x8*)&Bs[wn * 32 + fr][kg];
            bf16x8 bf1 = *(const bf16x8*)&Bs[wn * 32 + 16 + fr][kg];
            acc[0][0] = __builtin_amdgcn_mfma_f32_16x16x32_bf16(af0, bf0, acc[0][0], 0, 0, 0);
            acc[0][1] = __builtin_amdgcn_mfma_f32_16x16x32_bf16(af0, bf1, acc[0][1], 0, 0, 0);
            acc[1][0] = __builtin_amdgcn_mfma_f32_16x16x32_bf16(af1, bf0, acc[1][0], 0, 0, 0);
            acc[1][1] = __builtin_amdgcn_mfma_f32_16x16x32_bf16(af1, bf1, acc[1][1], 0, 0, 0);
        }

        float m[2][4];
        float msum = 0.f;
        #pragma unroll
        for (int fm = 0; fm < 2; ++fm)
            #pragma unroll
            for (int j = 0; j < 4; ++j) {
                m[fm][j] = smask[bm + wm * 32 + fm * 16 + rq + j];
                msum += m[fm][j];
            }
        float colsum[2];
        #pragma unroll
        for (int fn = 0; fn < 2; ++fn) {
            const float bv = b_sent[bn + wn * 32 + fn * 16 + fr];
            float s = 0.f;
            #pragma unroll
            for (int fm = 0; fm < 2; ++fm)
                #pragma unroll
                for (int j = 0; j < 4; ++j)
                    s = fmaf(selu_f(acc[fm][fn][j] + bv), m[fm][j], s);
            colsum[fn] = s;
        }
        #pragma unroll
        for (int fn = 0; fn < 2; ++fn) {
            colsum[fn] += __shfl_xor(colsum[fn], 16, 64);
            colsum[fn] += __shfl_xor(colsum[fn], 32, 64);
        }
        msum += __shfl_xor(msum, 16, 64);
        msum += __shfl_xor(msum, 32, 64);
        const float inv = 1.0f / fmaxf(msum, 1.0f);
        if (lane < 16) {
            const int g = 2 * (b >> 3) + wm;
            #pragma unroll
            for (int fn = 0; fn < 2; ++fn)
                mrev[(size_t)g * E_ + bn + wn * 32 + fn * 16 + fr] =
                    __float2bfloat16(colsum[fn] * inv);
        }
    }
    __syncthreads();
    __threadfence();
    if (tid == 0) atomicAdd(&fl[FG1], 1);

    if (b >= NCG * NKG) return;     // only blocks 0..24 continue

    // ================= Phase G2: blocks 0..7 =================
    if (b < 8) {
        if (tid == 0) spin_until(&fl[FG1], 256);
        __syncthreads();
        __threadfence();

        short (*As2)[72] = (short(*)[72])smem;                       //  9216 B
        short (*Bs2)[72] = (short(*)[72])(smem + 9216);              //  9216 B
        float (*cs)[2][2][16] = (float(*)[2][2][16])(smem + 18432);  //   512 B
        float (*ufl)[U_] = (float(*)[U_])(smem + 18944);             //  5120 B
        const int bn = b * 64;
        const int scol = (tid & 3) * 8;

        if (b == 0 && tid < 64) {
            const int r = tid;
            float ss = 0.f;
            #pragma unroll
            for (int j = 0; j < U_; ++j) {
                const float u = user_feats[r * U_ + j];
                ss = fmaf(u, u, ss);
            }
            const float nrm = fmaxf(sqrtf(ss), 1e-12f);
            #pragma unroll
            for (int j = 0; j < U_; ++j) {
                const float v = user_feats[r * U_ + j] / nrm * user_w[j];
                p_batch[(size_t)r * D_ + E_ + j] = v;
                ufl[r][j] = v;
            }
        }

        const short* Ag  = (const short*)mrev;
        const short* Btg = (const short*)(wT + (size_t)E_ * E_);

        f32x4 acc[2][2];
        #pragma unroll
        for (int i = 0; i < 2; ++i)
            #pragma unroll
            for (int j = 0; j < 2; ++j) acc[i][j] = (f32x4){0.f, 0.f, 0.f, 0.f};

        for (int k0 = 0; k0 < E_; k0 += 64) {
            __syncthreads();
            *(bf16x8*)&As2[srow][scol]      = *(const bf16x8*)&Ag[(size_t)srow * E_ + k0 + scol];
            *(bf16x8*)&As2[srow][scol + 32] = *(const bf16x8*)&Ag[(size_t)srow * E_ + k0 + scol + 32];
            *(bf16x8*)&Bs2[srow][scol]      = *(const bf16x8*)&Btg[(size_t)(bn + srow) * E_ + k0 + scol];
            *(bf16x8*)&Bs2[srow][scol + 32] = *(const bf16x8*)&Btg[(size_t)(bn + srow) * E_ + k0 + scol + 32];
            __syncthreads();
            #pragma unroll
            for (int ks = 0; ks < 64; ks += 32) {
                bf16x8 af0 = *(const bf16x8*)&As2[wm * 32 + fr][ks + kg];
                bf16x8 af1 = *(const bf16x8*)&As2[wm * 32 + 16 + fr][ks + kg];
                bf16x8 bf0 = *(const bf16x8*)&Bs2[wn * 32 + fr][ks + kg];
                bf16x8 bf1 = *(const bf16x8*)&Bs2[wn * 32 + 16 + fr][ks + kg];
                acc[0][0] = __builtin_amdgcn_mfma_f32_16x16x32_bf16(af0, bf0, acc[0][0], 0, 0, 0);
                acc[0][1] = __builtin_amdgcn_mfma_f32_16x16x32_bf16(af0, bf1, acc[0][1], 0, 0, 0);
                acc[1][0] = __builtin_amdgcn_mfma_f32_16x16x32_bf16(af1, bf0, acc[1][0], 0, 0, 0);
                acc[1][1] = __builtin_amdgcn_mfma_f32_16x16x32_bf16(af1, bf1, acc[1][1], 0, 0, 0);
            }
        }

        float colsum[2] = {0.f, 0.f};
        #pragma unroll
        for (int fm = 0; fm < 2; ++fm) {
            #pragma unroll
            for (int fn = 0; fn < 2; ++fn) {
                const int col = bn + wn * 32 + fn * 16 + fr;
                const float bv = b_rev[col];
                #pragma unroll
                for (int j = 0; j < 4; ++j) {
                    const int row = wm * 32 + fm * 16 + rq + j;
                    const float val = selu_f(acc[fm][fn][j] + bv);
                    p_batch[(size_t)row * D_ + col] = val;
                    colsum[fn] += val;
                }
            }
        }
        #pragma unroll
        for (int fn = 0; fn < 2; ++fn) {
            colsum[fn] += __shfl_xor(colsum[fn], 16, 64);
            colsum[fn] += __shfl_xor(colsum[fn], 32, 64);
        }
        if (lane < 16) {
            cs[wm][wn][0][fr] = colsum[0];
            cs[wm][wn][1][fr] = colsum[1];
        }
        __syncthreads();
        if (tid < 64) {
            const int wn2 = tid >> 5, fn2 = (tid >> 4) & 1, fr2 = tid & 15;
            const float s = cs[0][wn2][fn2][fr2] + cs[1][wn2][fn2][fr2];
            pbar[bn + wn2 * 32 + fn2 * 16 + fr2] = s * (1.0f / 64.0f);
        }
        if (b == 0 && tid < U_) {
            float s = 0.f;
            #pragma unroll 16
            for (int r = 0; r < 64; ++r) s += ufl[r][tid];
            pbar[E_ + tid] = s * (1.0f / 64.0f);
        }
        __syncthreads();
        __threadfence();
        if (tid == 0) atomicAdd(&fl[FG2], 1);
    }

    // ================= Phase D: blocks 0..24 =================
    {
        if (tid == 0) spin_until(&fl[FG2], 8);
        __syncthreads();
        __threadfence();

        float* pb = (float*)smem;                          // 512 B
        float (*red)[PCHUNK] = (float(*)[PCHUNK])(smem + 512);   // 1024 B
        const int cg = b % NCG, kgrp = b / NCG;
        const int cl = tid & (PCHUNK - 1);
        const int h  = tid >> 7;
        const int k0 = kgrp * PCHUNK;
        const int klen = min(PCHUNK, D_ - k0);

        if (tid < klen) pb[tid] = pbar[k0 + tid];
        __syncthreads();

        const int c = cg * PCHUNK + cl;
        float acc = 0.f;
        if (c < D_) {
            const int jb = h * 64;
            const int je = min(jb + 64, klen);
            for (int j = jb; j < je; ++j)
                acc = fmaf(pb[j], w_prod[(size_t)(k0 + j) * D_ + c], acc);
        }
        red[h][cl] = acc;
        __syncthreads();
        if (h == 0 && c < D_) part[kgrp * D_ + c] = red[0][cl] + red[1][cl];

        __syncthreads();
        __threadfence();
        __shared__ int is_last;
        if (tid == 0) is_last = (atomicAdd(&fl[FD], 1) == NCG * NKG - 1);
        __syncthreads();
        if (!is_last) return;
        __threadfence();

        float* hn = (float*)(smem + 1536);                 // 2128 B
        float (*rred)[64] = (float(*)[64])(smem + 3712);   // 1024 B
        float (*ppart)[28] = (float(*)[28])(smem + 4736);  // 1008 B
        for (int cc = tid; cc < D_; cc += 256) {
            float s = b_prod[cc];
            #pragma unroll
            for (int g = 0; g < NKG; ++g) s += part[g * D_ + cc];
            hn[cc] = selu_f(s);
        }
        __syncthreads();
        if (tid < L_ * 28) {
            const int o = tid / 28, ii = tid % 28;
            float s = 0.f;
            for (int k = ii; k < D_; k += 28)
                s = fmaf(hn[k], w_pff[(size_t)k * L_ + o], s);
            ppart[o][ii] = s;
        }
        {
            const int r = tid & 63, q = tid >> 6;
            float pr = 0.f;
            for (int k = q * 133; k < (q + 1) * 133; ++k)
                pr = fmaf(p_batch[(size_t)r * D_ + k], w_rff[k], pr);
            rred[q][r] = pr;
        }
        __syncthreads();
        if (tid < L_) {
            float s = 0.f;
            #pragma unroll
            for (int ii = 0; ii < 28; ++ii) s += ppart[tid][ii];
            out_p[tid] = selu_f(s + b_pff[tid]);
        }
        if (tid < 64)
            out_r[tid] = selu_f(rred[0][tid] + rred[1][tid] + rred[2][tid] + rred[3][tid]
                                + b_rff[0]);
    }
}

extern "C" void kernel_launch(void* const* d_in, const int* in_sizes, int n_in,
                              void* d_out, int out_size, void* d_ws, size_t ws_size,
                              hipStream_t stream) {
    const int*   inputs     = (const int*)  d_in[0];
    const float* user_feats = (const float*)d_in[1];
    const float* emb        = (const float*)d_in[2];
    const float* w_sent     = (const float*)d_in[3];
    const float* b_sent     = (const float*)d_in[4];
    const float* w_rev      = (const float*)d_in[5];
    const float* b_rev      = (const float*)d_in[6];
    const float* w_prod     = (const float*)d_in[7];
    const float* b_prod     = (const float*)d_in[8];
    const float* w_rff      = (const float*)d_in[9];
    const float* b_rff      = (const float*)d_in[10];
    const float* w_pff      = (const float*)d_in[11];
    const float* b_pff      = (const float*)d_in[12];
    const float* user_w     = (const float*)d_in[13];
    float* out = (float*)d_out;   // [0..8] p_stars, [9..72] r_stars

    float* ws = (float*)d_ws;
    __hip_bfloat16* sent_bf = (__hip_bfloat16*)(ws);            // 2048*512 bf16
    __hip_bfloat16* wT      = (__hip_bfloat16*)(ws + 524288);   // 2*512*512 bf16
    __hip_bfloat16* mrev    = (__hip_bfloat16*)(ws + 786432);   // 64*512 bf16
    float* smask   = ws + 802816;    // 2048
    float* p_batch = ws + 804864;    // 64*532
    float* part    = ws + 838912;    // 5*532
    float* pbar_ws = ws + 841600;    // 544
    int*   flags   = (int*)(ws + 842144);

    k_fused_A<<<NSENT + 512, 256, 0, stream>>>(inputs, emb, w_sent, w_rev,
                                               sent_bf, wT, smask, flags);
    k_tail<<<256, 256, 0, stream>>>(
        sent_bf, wT, b_sent, smask, b_rev, user_feats, user_w,
        w_prod, b_prod, w_pff, b_pff, w_rff, b_rff,
        mrev, p_batch, pbar_ws, part, flags, out, out + L_);
}